// Round 1
// baseline (347.388 us; speedup 1.0000x reference)
//
#include <hip/hip_runtime.h>
#include <hip/hip_bf16.h>

// CombinedGeomAttention, ALPHA=1.0:
//   scores = 0.125*sqrt(relu(|q|^2|k|^2 - (q.k)^2) + 1e-8)   [B,H,L,S]
//   out0 = softmax_s(scores) @ V   [B,L,H,E]
//   out1 = mean(scores)            scalar (scores >= 0)
// Flash-style: block = (b,h, 64 q-rows), 4 waves x 16 rows, K/V tiles of 64.
// QK^T in split-bf16 (hi/lo) MFMA for ~fp32 accuracy; PV in bf16 MFMA.

#define B_ 4
#define L_ 2048
#define S_ 2048
#define H_ 8
#define E_ 64
#define SCALE_ 0.125f
#define EPS_ 1e-8f
#define LDK 72   // padded LDS stride (shorts) to break bank conflicts

typedef __attribute__((ext_vector_type(8))) short bf16x8;
typedef __attribute__((ext_vector_type(4))) short bf16x4v;
typedef __attribute__((ext_vector_type(4))) float f32x4;

static __device__ __forceinline__ short f2bf(float x) {
  union { float f; unsigned u; } v; v.f = x;
  unsigned r = (v.u + 0x7FFF + ((v.u >> 16) & 1)) >> 16;   // RNE
  return (short)(unsigned short)r;
}
static __device__ __forceinline__ float bf2f(short h) {
  union { unsigned u; float f; } v; v.u = ((unsigned)(unsigned short)h) << 16;
  return v.f;
}

__launch_bounds__(256, 2)
__global__ void geom_attn_kernel(const float* __restrict__ Q,
                                 const float* __restrict__ K,
                                 const float* __restrict__ V,
                                 float* __restrict__ out,
                                 float* __restrict__ score_sum) {
  __shared__ __align__(16) short Khi[64 * LDK];
  __shared__ __align__(16) short Klo[64 * LDK];
  __shared__ __align__(16) short Vt[64 * LDK];      // Vt[e][s]
  __shared__ __align__(16) short Plds[4][16 * LDK]; // per-wave P tile [16 rows][64 s]
  __shared__ float kn2[64];
  __shared__ float qn2[64];

  const int tid  = threadIdx.x;
  const int lane = tid & 63;
  const int w    = tid >> 6;      // wave 0..3
  const int g    = lane >> 4;     // 0..3
  const int c    = lane & 15;     // 0..15

  const int bidx = blockIdx.x;
  const int qt = bidx & 31;          // L/64
  const int h  = (bidx >> 5) & 7;
  const int b  = bidx >> 8;
  const int q0 = qt * 64;

  const size_t bh_base = (size_t)b * L_ * (H_ * E_) + (size_t)h * E_;
  const int row_stride = H_ * E_;  // 512 floats

  // ---- load per-wave Q fragments (rows w*16+c), split hi/lo, compute qn2
  bf16x8 qhi[2], qlo[2];
  {
    const int qrow = q0 + w * 16 + c;
    const float* qp = Q + bh_base + (size_t)qrow * row_stride;
    float qreg[16];
#pragma unroll
    for (int ch = 0; ch < 2; ++ch) {
      const float4 a = *reinterpret_cast<const float4*>(qp + ch * 32 + g * 8);
      const float4 bq = *reinterpret_cast<const float4*>(qp + ch * 32 + g * 8 + 4);
      qreg[ch * 8 + 0] = a.x;  qreg[ch * 8 + 1] = a.y;
      qreg[ch * 8 + 2] = a.z;  qreg[ch * 8 + 3] = a.w;
      qreg[ch * 8 + 4] = bq.x; qreg[ch * 8 + 5] = bq.y;
      qreg[ch * 8 + 6] = bq.z; qreg[ch * 8 + 7] = bq.w;
    }
    float qs = 0.f;
#pragma unroll
    for (int ch = 0; ch < 2; ++ch)
#pragma unroll
      for (int j = 0; j < 8; ++j) {
        float x = qreg[ch * 8 + j];
        qs += x * x;
        short hs = f2bf(x);
        qhi[ch][j] = hs;
        qlo[ch][j] = f2bf(x - bf2f(hs));
      }
    qs += __shfl_xor(qs, 16);
    qs += __shfl_xor(qs, 32);
    if (lane < 16) qn2[w * 16 + c] = qs;   // lane<16 => g==0, c==lane
  }
  __syncthreads();
  float qn2row[4];
#pragma unroll
  for (int i = 0; i < 4; ++i) qn2row[i] = qn2[w * 16 + g * 4 + i];

  // softmax running state (rows 4g+i of this wave's 16-row tile)
  float m_i[4]  = {0.f, 0.f, 0.f, 0.f};    // scores >= 0, so 0 is a safe init
  float lsum[4] = {0.f, 0.f, 0.f, 0.f};    // per-lane partial row sums
  f32x4 o[4];
#pragma unroll
  for (int dt = 0; dt < 4; ++dt) o[dt] = (f32x4){0.f, 0.f, 0.f, 0.f};
  float ssum = 0.f;

  for (int kt = 0; kt < S_ / 64; ++kt) {
    __syncthreads();   // A: previous tile's LDS reads complete

    // ---- stage K (hi/lo) and V^T tiles; compute kn2 in fp32 on the fly
    {
      const int r0 = tid >> 4;     // 0..15
      const int c4 = tid & 15;     // float4 column
      const size_t kbase = bh_base + (size_t)(kt * 64) * row_stride + c4 * 4;
      float part[4];
#pragma unroll
      for (int i = 0; i < 4; ++i) {
        const int r = r0 + 16 * i;
        const float4 kv = *reinterpret_cast<const float4*>(K + kbase + (size_t)r * row_stride);
        part[i] = kv.x * kv.x + kv.y * kv.y + kv.z * kv.z + kv.w * kv.w;
        const short h0 = f2bf(kv.x), h1 = f2bf(kv.y), h2 = f2bf(kv.z), h3 = f2bf(kv.w);
        bf16x4v hv = {h0, h1, h2, h3};
        *reinterpret_cast<bf16x4v*>(&Khi[r * LDK + c4 * 4]) = hv;
        bf16x4v lv = {f2bf(kv.x - bf2f(h0)), f2bf(kv.y - bf2f(h1)),
                      f2bf(kv.z - bf2f(h2)), f2bf(kv.w - bf2f(h3))};
        *reinterpret_cast<bf16x4v*>(&Klo[r * LDK + c4 * 4]) = lv;
        const float4 vv = *reinterpret_cast<const float4*>(V + kbase + (size_t)r * row_stride);
        Vt[(c4 * 4 + 0) * LDK + r] = f2bf(vv.x);
        Vt[(c4 * 4 + 1) * LDK + r] = f2bf(vv.y);
        Vt[(c4 * 4 + 2) * LDK + r] = f2bf(vv.z);
        Vt[(c4 * 4 + 3) * LDK + r] = f2bf(vv.w);
      }
#pragma unroll
      for (int m = 1; m < 16; m <<= 1)
#pragma unroll
        for (int i = 0; i < 4; ++i) part[i] += __shfl_xor(part[i], m);
      if (c4 < 4) kn2[r0 + 16 * c4] = part[c4];
    }
    __syncthreads();   // B: staging + kn2 visible

    // ---- scores: 16x64 per wave, split-bf16 MFMA
    float sv[4][4];
    float tm[4] = {0.f, 0.f, 0.f, 0.f};
#pragma unroll
    for (int sub = 0; sub < 4; ++sub) {
      const int s = sub * 16 + c;
      f32x4 acc = (f32x4){0.f, 0.f, 0.f, 0.f};
#pragma unroll
      for (int ch = 0; ch < 2; ++ch) {
        const int e = ch * 32 + g * 8;
        const bf16x8 bh = *reinterpret_cast<const bf16x8*>(&Khi[s * LDK + e]);
        const bf16x8 bl = *reinterpret_cast<const bf16x8*>(&Klo[s * LDK + e]);
        acc = __builtin_amdgcn_mfma_f32_16x16x32_bf16(qhi[ch], bh, acc, 0, 0, 0);
        acc = __builtin_amdgcn_mfma_f32_16x16x32_bf16(qlo[ch], bh, acc, 0, 0, 0);
        acc = __builtin_amdgcn_mfma_f32_16x16x32_bf16(qhi[ch], bl, acc, 0, 0, 0);
      }
      const float kn = kn2[s];
#pragma unroll
      for (int i = 0; i < 4; ++i) {
        const float dot = acc[i];
        float w2 = qn2row[i] * kn - dot * dot;
        w2 = fmaxf(w2, 0.f) + EPS_;
        const float sc = SCALE_ * sqrtf(w2);
        sv[sub][i] = sc;
        tm[i] = fmaxf(tm[i], sc);
        ssum += sc;
      }
    }
    // row max across the 16 lanes of the group
#pragma unroll
    for (int m = 1; m < 16; m <<= 1)
#pragma unroll
      for (int i = 0; i < 4; ++i) tm[i] = fmaxf(tm[i], __shfl_xor(tm[i], m));

    float r_[4];
#pragma unroll
    for (int i = 0; i < 4; ++i) {
      const float mn = fmaxf(m_i[i], tm[i]);
      r_[i] = __expf(m_i[i] - mn);
      m_i[i] = mn;
      lsum[i] *= r_[i];
    }
#pragma unroll
    for (int dt = 0; dt < 4; ++dt)
#pragma unroll
      for (int i = 0; i < 4; ++i) o[dt][i] *= r_[i];

    // P = exp(s - m), write to wave-private LDS tile for re-layout
#pragma unroll
    for (int sub = 0; sub < 4; ++sub) {
      const int s = sub * 16 + c;
#pragma unroll
      for (int i = 0; i < 4; ++i) {
        const float p = __expf(sv[sub][i] - m_i[i]);
        lsum[i] += p;
        Plds[w][(g * 4 + i) * LDK + s] = f2bf(p);
      }
    }
    __syncthreads();   // D: P visible (block-wide sync keeps waves uniform)

    // ---- PV: o[16x64] += P[16x64] @ V[64x64]
#pragma unroll
    for (int ks = 0; ks < 2; ++ks) {
      const bf16x8 pa = *reinterpret_cast<const bf16x8*>(&Plds[w][c * LDK + ks * 32 + g * 8]);
#pragma unroll
      for (int dt = 0; dt < 4; ++dt) {
        const bf16x8 vb = *reinterpret_cast<const bf16x8*>(&Vt[(dt * 16 + c) * LDK + ks * 32 + g * 8]);
        o[dt] = __builtin_amdgcn_mfma_f32_16x16x32_bf16(pa, vb, o[dt], 0, 0, 0);
      }
    }
  }

  // ---- finalize: complete row sums, normalize, store
#pragma unroll
  for (int m = 1; m < 16; m <<= 1)
#pragma unroll
    for (int i = 0; i < 4; ++i) lsum[i] += __shfl_xor(lsum[i], m);

#pragma unroll
  for (int i = 0; i < 4; ++i) {
    const float inv = 1.0f / lsum[i];
    const int qrow = q0 + w * 16 + g * 4 + i;
    float* op = out + (size_t)b * L_ * (H_ * E_) + (size_t)qrow * row_stride + (size_t)h * E_;
#pragma unroll
    for (int dt = 0; dt < 4; ++dt)
      op[dt * 16 + c] = o[dt][i] * inv;
  }

  // ---- scalar: sum of scores
#pragma unroll
  for (int m = 1; m < 64; m <<= 1) ssum += __shfl_xor(ssum, m);
  if (lane == 0) atomicAdd(score_sum, ssum);
}

__global__ void geom_attn_finalize(const float* __restrict__ ws, float* __restrict__ out) {
  out[(size_t)B_ * L_ * H_ * E_] = ws[0] * (1.0f / ((float)B_ * H_ * (float)L_ * (float)S_));
}

extern "C" void kernel_launch(void* const* d_in, const int* in_sizes, int n_in,
                              void* d_out, int out_size, void* d_ws, size_t ws_size,
                              hipStream_t stream) {
  const float* Q = (const float*)d_in[0];
  const float* K = (const float*)d_in[1];
  const float* V = (const float*)d_in[2];
  float* out = (float*)d_out;
  float* ws  = (float*)d_ws;

  hipMemsetAsync(d_ws, 0, sizeof(float), stream);

  dim3 grid(B_ * H_ * (L_ / 64));   // 1024 blocks
  dim3 block(256);
  geom_attn_kernel<<<grid, block, 0, stream>>>(Q, K, V, out, ws);
  geom_attn_finalize<<<1, 1, 0, stream>>>(ws, out);
}

// Round 2
// 209.467 us; speedup vs baseline: 1.6584x; 1.6584x over previous
//
#include <hip/hip_runtime.h>
#include <hip/hip_bf16.h>

// CombinedGeomAttention, ALPHA=1:
//   s = 0.125*sqrt(relu(|q|^2|k|^2 - (q.k)^2) + 1e-8); out0 = softmax_s(s) @ V; out1 = mean(s)
// Round 2: prepass converts K/V to bf16 (V transposed) + key norms ONCE, tiles stored
// pre-swizzled for conflict-free ds_read_b128 after linear global_load_lds staging.
// Attention: no online max (scores bounded), log2-domain exp, 1-barrier double buffer.

#define B_ 4
#define L_ 2048
#define S_ 2048
#define H_ 8
#define E_ 64
#define EPS_ 1e-8f
#define SC2_ 0.18033688011112042f   // 0.125 * log2(e)
#define LN2_ 0.6931471805599453f
#define LDP 72
#define ROWSTR (H_ * E_)            // 512 floats

#define K_OFF 0
#define V_OFF 8388608
#define KN_OFF 16777216
#define SS_OFF 17039360
#define WS_NEED 17039364

typedef __attribute__((ext_vector_type(8))) short bf16x8;
typedef __attribute__((ext_vector_type(4))) short bf16x4v;
typedef __attribute__((ext_vector_type(4))) float f32x4;

static __device__ __forceinline__ short f2bf_rne(float x) {
  union { float f; unsigned u; } v; v.f = x;
  unsigned r = (v.u + 0x7FFF + ((v.u >> 16) & 1)) >> 16;
  return (short)(unsigned short)r;
}
static __device__ __forceinline__ float bf2f(short h) {
  union { unsigned u; float f; } v; v.u = ((unsigned)(unsigned short)h) << 16;
  return v.f;
}
static __device__ __forceinline__ float fast_sqrt(float x) {
  float r; asm("v_sqrt_f32 %0, %1" : "=v"(r) : "v"(x)); return r;
}
static __device__ __forceinline__ float fast_exp2(float x) {
  float r; asm("v_exp_f32 %0, %1" : "=v"(r) : "v"(x)); return r;
}
static __device__ __forceinline__ void gload16(const void* g, void* l) {
  __builtin_amdgcn_global_load_lds((const __attribute__((address_space(1))) void*)g,
                                   (__attribute__((address_space(3))) void*)l, 16, 0, 0);
}

// ---------------- prepass: K -> bf16 swizzled [bh,tile][s][e] + |k|^2 ----------------
__global__ void prep_k(const float* __restrict__ K, short* __restrict__ Kg,
                       float* __restrict__ kn2g) {
  const int tid = threadIdx.x;
  const int bidx = blockIdx.x;          // bh*32 + st
  const int st = bidx & 31;
  const int bh = bidx >> 5;
  const int b = bh >> 3, h = bh & 7;
  const size_t src_base = (size_t)b * (L_ * ROWSTR) + (size_t)(st * 64) * ROWSTR + (size_t)h * E_;
  short* dst = Kg + (size_t)bidx * 4096;

  const int s = tid >> 2;
  float part = 0.f;
#pragma unroll
  for (int q = 0; q < 2; ++q) {
    const int ci = 2 * tid + q;
    const int ch = ci & 7;
    const int esrc = (ch ^ (s & 7)) * 8;
    const float* sp = K + src_base + (size_t)s * ROWSTR + esrc;
    const float4 a = *reinterpret_cast<const float4*>(sp);
    const float4 c4 = *reinterpret_cast<const float4*>(sp + 4);
    part += a.x*a.x + a.y*a.y + a.z*a.z + a.w*a.w
          + c4.x*c4.x + c4.y*c4.y + c4.z*c4.z + c4.w*c4.w;
    bf16x8 o;
    o[0]=f2bf_rne(a.x); o[1]=f2bf_rne(a.y); o[2]=f2bf_rne(a.z); o[3]=f2bf_rne(a.w);
    o[4]=f2bf_rne(c4.x); o[5]=f2bf_rne(c4.y); o[6]=f2bf_rne(c4.z); o[7]=f2bf_rne(c4.w);
    *reinterpret_cast<bf16x8*>(dst + s * 64 + ch * 8) = o;
  }
  part += __shfl_xor(part, 1);
  part += __shfl_xor(part, 2);
  if ((tid & 3) == 0) kn2g[(size_t)bidx * 64 + s] = part;
}

// ---------------- prepass: V -> bf16 transposed+swizzled [bh,tile][e][s] ----------------
__global__ void prep_v(const float* __restrict__ V, short* __restrict__ Vg) {
  __shared__ __align__(16) short TT[64][72];
  const int tid = threadIdx.x;
  const int bidx = blockIdx.x;
  const int st = bidx & 31;
  const int bh = bidx >> 5;
  const int b = bh >> 3, h = bh & 7;
  const size_t src_base = (size_t)b * (L_ * ROWSTR) + (size_t)(st * 64) * ROWSTR + (size_t)h * E_;
  short* dst = Vg + (size_t)bidx * 4096;

  const int s = tid >> 2;
  const int e0 = (tid & 3) * 16;
  const float* sp = V + src_base + (size_t)s * ROWSTR + e0;
#pragma unroll
  for (int q = 0; q < 4; ++q) {
    const float4 a = *reinterpret_cast<const float4*>(sp + q * 4);
    TT[e0 + q*4 + 0][s] = f2bf_rne(a.x);
    TT[e0 + q*4 + 1][s] = f2bf_rne(a.y);
    TT[e0 + q*4 + 2][s] = f2bf_rne(a.z);
    TT[e0 + q*4 + 3][s] = f2bf_rne(a.w);
  }
  __syncthreads();
  const int e = s;
#pragma unroll
  for (int q = 0; q < 2; ++q) {
    const int ci = 2 * tid + q;
    const int ch = ci & 7;
    const int ssrc = (ch ^ (e & 7)) * 8;
    const bf16x8 v = *reinterpret_cast<const bf16x8*>(&TT[e][ssrc]);
    *reinterpret_cast<bf16x8*>(dst + e * 64 + ch * 8) = v;
  }
}

// ---------------- main attention ----------------
__launch_bounds__(256, 2)
__global__ void geom_attn(const float* __restrict__ Q,
                          const short* __restrict__ Kg,
                          const short* __restrict__ Vg,
                          const float* __restrict__ kn2g,
                          float* __restrict__ out,
                          float* __restrict__ ssum_g) {
  __shared__ __align__(16) short Kl[2][4096];
  __shared__ __align__(16) short Vl[2][4096];
  __shared__ __align__(16) short Plds[4][16 * LDP];

  const int tid = threadIdx.x;
  const int lane = tid & 63;
  const int w = tid >> 6;
  const int g = lane >> 4;
  const int c = lane & 15;
  const int cx = c & 7;

  // XCD-chunked swizzle: 1024 blocks, 8 XCDs -> each XCD owns 4 consecutive (b,h)
  const int vbk = ((blockIdx.x & 7) << 7) + (blockIdx.x >> 3);
  const int qt = vbk & 31;
  const int bh = vbk >> 5;
  const int b = bh >> 3, h = bh & 7;
  const int q0 = qt * 64;

  const size_t qbase = (size_t)b * (L_ * ROWSTR) + (size_t)h * E_;

  // ---- Q fragments (bf16) + |q|^2 (fp32 exact)
  bf16x8 qa[2];
  float qn2row[4];
  {
    const int qrow = q0 + w * 16 + c;
    const float* qp = Q + qbase + (size_t)qrow * ROWSTR;
    float qs = 0.f;
#pragma unroll
    for (int ch = 0; ch < 2; ++ch) {
      const float4 a = *reinterpret_cast<const float4*>(qp + ch * 32 + g * 8);
      const float4 b4 = *reinterpret_cast<const float4*>(qp + ch * 32 + g * 8 + 4);
      qa[ch][0]=f2bf_rne(a.x); qa[ch][1]=f2bf_rne(a.y); qa[ch][2]=f2bf_rne(a.z); qa[ch][3]=f2bf_rne(a.w);
      qa[ch][4]=f2bf_rne(b4.x); qa[ch][5]=f2bf_rne(b4.y); qa[ch][6]=f2bf_rne(b4.z); qa[ch][7]=f2bf_rne(b4.w);
      qs += a.x*a.x + a.y*a.y + a.z*a.z + a.w*a.w
          + b4.x*b4.x + b4.y*b4.y + b4.z*b4.z + b4.w*b4.w;
    }
    qs += __shfl_xor(qs, 16);
    qs += __shfl_xor(qs, 32);
#pragma unroll
    for (int i = 0; i < 4; ++i) qn2row[i] = __shfl(qs, g * 4 + i);
  }

  float lsum[4] = {0.f, 0.f, 0.f, 0.f};
  f32x4 o[4];
#pragma unroll
  for (int dt = 0; dt < 4; ++dt) o[dt] = (f32x4){0.f, 0.f, 0.f, 0.f};
  float ssum = 0.f;

  const char* Ksrc = (const char*)(Kg + (size_t)(bh * 32) * 4096);
  const char* Vsrc = (const char*)(Vg + (size_t)(bh * 32) * 4096);
  const float* knb = kn2g + (size_t)(bh * 32) * 64;

  const int wb = w * 2048;  // wave's byte range within an 8KB tile

  // prologue: stage tile 0 into buffer 0
  gload16(Ksrc + wb + lane * 16,        (char*)&Kl[0][0] + wb);
  gload16(Ksrc + wb + 1024 + lane * 16, (char*)&Kl[0][0] + wb + 1024);
  gload16(Vsrc + wb + lane * 16,        (char*)&Vl[0][0] + wb);
  gload16(Vsrc + wb + 1024 + lane * 16, (char*)&Vl[0][0] + wb + 1024);

  for (int kt = 0; kt < 32; ++kt) {
    const int cb = kt & 1;
    __syncthreads();  // drains vmcnt: tile kt staged; all waves done with buf cb^1

    if (kt + 1 < 32) {
      const char* ks2 = Ksrc + (size_t)(kt + 1) * 8192;
      const char* vs2 = Vsrc + (size_t)(kt + 1) * 8192;
      gload16(ks2 + wb + lane * 16,        (char*)&Kl[cb ^ 1][0] + wb);
      gload16(ks2 + wb + 1024 + lane * 16, (char*)&Kl[cb ^ 1][0] + wb + 1024);
      gload16(vs2 + wb + lane * 16,        (char*)&Vl[cb ^ 1][0] + wb);
      gload16(vs2 + wb + 1024 + lane * 16, (char*)&Vl[cb ^ 1][0] + wb + 1024);
    }

    float kn_r[4];
#pragma unroll
    for (int sub = 0; sub < 4; ++sub) kn_r[sub] = knb[kt * 64 + sub * 16 + c];

    // ---- QK^T + scores + P (log2 domain, no max subtraction)
#pragma unroll
    for (int sub = 0; sub < 4; ++sub) {
      const int s = sub * 16 + c;
      f32x4 acc = (f32x4){0.f, 0.f, 0.f, 0.f};
#pragma unroll
      for (int ch = 0; ch < 2; ++ch) {
        const int idx = s * 64 + (((ch * 4 + g) ^ cx) << 3);
        const bf16x8 bh8 = *reinterpret_cast<const bf16x8*>(&Kl[cb][idx]);
        acc = __builtin_amdgcn_mfma_f32_16x16x32_bf16(qa[ch], bh8, acc, 0, 0, 0);
      }
#pragma unroll
      for (int i = 0; i < 4; ++i) {
        const float dot = acc[i];
        const float w2 = fmaxf(fmaf(-dot, dot, qn2row[i] * kn_r[sub]), EPS_);
        const float s2 = SC2_ * fast_sqrt(w2);   // score * log2(e)
        ssum += s2;
        const float p = fast_exp2(s2);           // exp(score)
        union { float f; unsigned u; } pu; pu.f = p;
        union { unsigned u; float f; } pt; pt.u = pu.u & 0xffff0000u;
        lsum[i] += pt.f;                          // sum the bf16-truncated p (exact norm)
        Plds[w][(g * 4 + i) * LDP + s] = (short)(unsigned short)(pu.u >> 16);
      }
    }

    // ---- PV (wave-private P; lgkmcnt ordering suffices, no barrier)
#pragma unroll
    for (int ks = 0; ks < 2; ++ks) {
      const bf16x8 pa = *reinterpret_cast<const bf16x8*>(&Plds[w][c * LDP + ks * 32 + g * 8]);
#pragma unroll
      for (int dt = 0; dt < 4; ++dt) {
        const int er = dt * 16 + c;
        const int idx = er * 64 + (((ks * 4 + g) ^ cx) << 3);
        const bf16x8 vb8 = *reinterpret_cast<const bf16x8*>(&Vl[cb][idx]);
        o[dt] = __builtin_amdgcn_mfma_f32_16x16x32_bf16(pa, vb8, o[dt], 0, 0, 0);
      }
    }
  }

  // ---- epilogue: row sums, normalize, store
#pragma unroll
  for (int m = 1; m < 16; m <<= 1)
#pragma unroll
    for (int i = 0; i < 4; ++i) lsum[i] += __shfl_xor(lsum[i], m);

#pragma unroll
  for (int i = 0; i < 4; ++i) {
    const float inv = 1.0f / lsum[i];
    const int qrow = q0 + w * 16 + g * 4 + i;
    float* op = out + (size_t)b * (L_ * ROWSTR) + (size_t)qrow * ROWSTR + (size_t)h * E_;
#pragma unroll
    for (int dt = 0; dt < 4; ++dt)
      op[dt * 16 + c] = o[dt][i] * inv;
  }

#pragma unroll
  for (int m = 1; m < 64; m <<= 1) ssum += __shfl_xor(ssum, m);
  if (lane == 0) atomicAdd(ssum_g, ssum);
}

__global__ void geom_fin(const float* __restrict__ ws, float* __restrict__ out) {
  out[(size_t)B_ * L_ * H_ * E_] = ws[0] * (LN2_ / 134217728.0f);
}

// ================= fallback (round-1 kernel) if ws too small =================
__launch_bounds__(256, 2)
__global__ void geom_attn_v1(const float* __restrict__ Q, const float* __restrict__ K,
                             const float* __restrict__ V, float* __restrict__ out,
                             float* __restrict__ score_sum) {
  __shared__ __align__(16) short Khi[64 * LDP];
  __shared__ __align__(16) short Klo[64 * LDP];
  __shared__ __align__(16) short Vt[64 * LDP];
  __shared__ __align__(16) short Plds[4][16 * LDP];
  __shared__ float kn2[64];
  __shared__ float qn2[64];

  const int tid = threadIdx.x;
  const int lane = tid & 63;
  const int w = tid >> 6;
  const int g = lane >> 4;
  const int c = lane & 15;
  const int bidx = blockIdx.x;
  const int qt = bidx & 31;
  const int h = (bidx >> 5) & 7;
  const int b = bidx >> 8;
  const int q0 = qt * 64;
  const size_t bh_base = (size_t)b * L_ * ROWSTR + (size_t)h * E_;

  bf16x8 qhi[2], qlo[2];
  {
    const int qrow = q0 + w * 16 + c;
    const float* qp = Q + bh_base + (size_t)qrow * ROWSTR;
    float qs = 0.f;
#pragma unroll
    for (int ch = 0; ch < 2; ++ch) {
      const float4 a = *reinterpret_cast<const float4*>(qp + ch * 32 + g * 8);
      const float4 bq = *reinterpret_cast<const float4*>(qp + ch * 32 + g * 8 + 4);
      const float xs[8] = {a.x,a.y,a.z,a.w,bq.x,bq.y,bq.z,bq.w};
#pragma unroll
      for (int j = 0; j < 8; ++j) {
        const float x = xs[j];
        qs += x * x;
        const short hs = f2bf_rne(x);
        qhi[ch][j] = hs;
        qlo[ch][j] = f2bf_rne(x - bf2f(hs));
      }
    }
    qs += __shfl_xor(qs, 16);
    qs += __shfl_xor(qs, 32);
    if (lane < 16) qn2[w * 16 + c] = qs;
  }
  __syncthreads();
  float qn2row[4];
#pragma unroll
  for (int i = 0; i < 4; ++i) qn2row[i] = qn2[w * 16 + g * 4 + i];

  float m_i[4] = {0,0,0,0}, lsum[4] = {0,0,0,0};
  f32x4 o[4];
#pragma unroll
  for (int dt = 0; dt < 4; ++dt) o[dt] = (f32x4){0,0,0,0};
  float ssum = 0.f;

  for (int kt = 0; kt < S_ / 64; ++kt) {
    __syncthreads();
    {
      const int r0 = tid >> 4, c4 = tid & 15;
      const size_t kbase = bh_base + (size_t)(kt * 64) * ROWSTR + c4 * 4;
      float part[4];
#pragma unroll
      for (int i = 0; i < 4; ++i) {
        const int r = r0 + 16 * i;
        const float4 kv = *reinterpret_cast<const float4*>(K + kbase + (size_t)r * ROWSTR);
        part[i] = kv.x*kv.x + kv.y*kv.y + kv.z*kv.z + kv.w*kv.w;
        const short h0 = f2bf_rne(kv.x), h1 = f2bf_rne(kv.y), h2 = f2bf_rne(kv.z), h3 = f2bf_rne(kv.w);
        bf16x4v hv = {h0, h1, h2, h3};
        *reinterpret_cast<bf16x4v*>(&Khi[r * LDP + c4 * 4]) = hv;
        bf16x4v lv = {f2bf_rne(kv.x - bf2f(h0)), f2bf_rne(kv.y - bf2f(h1)),
                      f2bf_rne(kv.z - bf2f(h2)), f2bf_rne(kv.w - bf2f(h3))};
        *reinterpret_cast<bf16x4v*>(&Klo[r * LDP + c4 * 4]) = lv;
        const float4 vv = *reinterpret_cast<const float4*>(V + kbase + (size_t)r * ROWSTR);
        Vt[(c4 * 4 + 0) * LDP + r] = f2bf_rne(vv.x);
        Vt[(c4 * 4 + 1) * LDP + r] = f2bf_rne(vv.y);
        Vt[(c4 * 4 + 2) * LDP + r] = f2bf_rne(vv.z);
        Vt[(c4 * 4 + 3) * LDP + r] = f2bf_rne(vv.w);
      }
#pragma unroll
      for (int m = 1; m < 16; m <<= 1)
#pragma unroll
        for (int i = 0; i < 4; ++i) part[i] += __shfl_xor(part[i], m);
      if (c4 < 4) kn2[r0 + 16 * c4] = part[c4];
    }
    __syncthreads();

    float sv[4][4];
    float tm[4] = {0,0,0,0};
#pragma unroll
    for (int sub = 0; sub < 4; ++sub) {
      const int s = sub * 16 + c;
      f32x4 acc = (f32x4){0,0,0,0};
#pragma unroll
      for (int ch = 0; ch < 2; ++ch) {
        const int e = ch * 32 + g * 8;
        const bf16x8 bh8 = *reinterpret_cast<const bf16x8*>(&Khi[s * LDP + e]);
        const bf16x8 bl8 = *reinterpret_cast<const bf16x8*>(&Klo[s * LDP + e]);
        acc = __builtin_amdgcn_mfma_f32_16x16x32_bf16(qhi[ch], bh8, acc, 0, 0, 0);
        acc = __builtin_amdgcn_mfma_f32_16x16x32_bf16(qlo[ch], bh8, acc, 0, 0, 0);
        acc = __builtin_amdgcn_mfma_f32_16x16x32_bf16(qhi[ch], bl8, acc, 0, 0, 0);
      }
      const float kn = kn2[s];
#pragma unroll
      for (int i = 0; i < 4; ++i) {
        const float dot = acc[i];
        float w2 = fmaxf(qn2row[i] * kn - dot * dot, 0.f) + EPS_;
        const float sc = 0.125f * sqrtf(w2);
        sv[sub][i] = sc;
        tm[i] = fmaxf(tm[i], sc);
        ssum += sc;
      }
    }
#pragma unroll
    for (int m = 1; m < 16; m <<= 1)
#pragma unroll
      for (int i = 0; i < 4; ++i) tm[i] = fmaxf(tm[i], __shfl_xor(tm[i], m));
    float r_[4];
#pragma unroll
    for (int i = 0; i < 4; ++i) {
      const float mn = fmaxf(m_i[i], tm[i]);
      r_[i] = __expf(m_i[i] - mn);
      m_i[i] = mn;
      lsum[i] *= r_[i];
    }
#pragma unroll
    for (int dt = 0; dt < 4; ++dt)
#pragma unroll
      for (int i = 0; i < 4; ++i) o[dt][i] *= r_[i];
#pragma unroll
    for (int sub = 0; sub < 4; ++sub) {
      const int s = sub * 16 + c;
#pragma unroll
      for (int i = 0; i < 4; ++i) {
        const float p = __expf(sv[sub][i] - m_i[i]);
        lsum[i] += p;
        Plds[w][(g * 4 + i) * LDP + s] = f2bf_rne(p);
      }
    }
    __syncthreads();
#pragma unroll
    for (int ks = 0; ks < 2; ++ks) {
      const bf16x8 pa = *reinterpret_cast<const bf16x8*>(&Plds[w][c * LDP + ks * 32 + g * 8]);
#pragma unroll
      for (int dt = 0; dt < 4; ++dt) {
        const bf16x8 vb8 = *reinterpret_cast<const bf16x8*>(&Vt[(dt * 16 + c) * LDP + ks * 32 + g * 8]);
        o[dt] = __builtin_amdgcn_mfma_f32_16x16x32_bf16(pa, vb8, o[dt], 0, 0, 0);
      }
    }
  }
#pragma unroll
  for (int m = 1; m < 16; m <<= 1)
#pragma unroll
    for (int i = 0; i < 4; ++i) lsum[i] += __shfl_xor(lsum[i], m);
#pragma unroll
  for (int i = 0; i < 4; ++i) {
    const float inv = 1.0f / lsum[i];
    const int qrow = q0 + w * 16 + g * 4 + i;
    float* op = out + (size_t)b * L_ * ROWSTR + (size_t)qrow * ROWSTR + (size_t)h * E_;
#pragma unroll
    for (int dt = 0; dt < 4; ++dt) op[dt * 16 + c] = o[dt][i] * inv;
  }
#pragma unroll
  for (int m = 1; m < 64; m <<= 1) ssum += __shfl_xor(ssum, m);
  if (lane == 0) atomicAdd(score_sum, ssum);
}

__global__ void geom_fin_v1(const float* __restrict__ ws, float* __restrict__ out) {
  out[(size_t)B_ * L_ * H_ * E_] = ws[0] * (1.0f / 134217728.0f);
}

extern "C" void kernel_launch(void* const* d_in, const int* in_sizes, int n_in,
                              void* d_out, int out_size, void* d_ws, size_t ws_size,
                              hipStream_t stream) {
  const float* Q = (const float*)d_in[0];
  const float* K = (const float*)d_in[1];
  const float* V = (const float*)d_in[2];
  float* out = (float*)d_out;

  if (ws_size >= (size_t)WS_NEED) {
    short* Kg = (short*)((char*)d_ws + K_OFF);
    short* Vg = (short*)((char*)d_ws + V_OFF);
    float* kn2g = (float*)((char*)d_ws + KN_OFF);
    float* ss = (float*)((char*)d_ws + SS_OFF);
    hipMemsetAsync(ss, 0, sizeof(float), stream);
    prep_k<<<dim3(1024), dim3(256), 0, stream>>>(K, Kg, kn2g);
    prep_v<<<dim3(1024), dim3(256), 0, stream>>>(V, Vg);
    geom_attn<<<dim3(1024), dim3(256), 0, stream>>>(Q, Kg, Vg, kn2g, out, ss);
    geom_fin<<<dim3(1), dim3(1), 0, stream>>>(ss, out);
  } else {
    float* ss = (float*)d_ws;
    hipMemsetAsync(ss, 0, sizeof(float), stream);
    geom_attn_v1<<<dim3(1024), dim3(256), 0, stream>>>(Q, K, V, out, ss);
    geom_fin_v1<<<dim3(1), dim3(1), 0, stream>>>(ss, out);
  }
}

// Round 3
// 193.755 us; speedup vs baseline: 1.7929x; 1.0811x over previous
//
#include <hip/hip_runtime.h>
#include <hip/hip_bf16.h>

// CombinedGeomAttention, ALPHA=1:
//   s = 0.125*sqrt(relu(|q|^2|k|^2 - (q.k)^2) + 1e-8); out0 = softmax_s(s) @ V; out1 = mean(s)
// Round 3: occupancy 2->4 blocks/CU (V single-buffered + counted-vmcnt barrier),
// fused prepass with packed bf16 converts.

#define B_ 4
#define L_ 2048
#define S_ 2048
#define H_ 8
#define E_ 64
#define EPS_ 1e-8f
#define SC2_ 0.18033688011112042f   // 0.125 * log2(e)
#define LN2_ 0.6931471805599453f
#define LDP 72
#define ROWSTR (H_ * E_)            // 512 floats

#define K_OFF 0
#define V_OFF 8388608
#define KN_OFF 16777216
#define SS_OFF 17039360
#define WS_NEED 17039364

typedef __attribute__((ext_vector_type(8))) short bf16x8;
typedef __attribute__((ext_vector_type(4))) short bf16x4v;
typedef __attribute__((ext_vector_type(4))) float f32x4;

union bfr8 { bf16x8 v; unsigned u[4]; };

static __device__ __forceinline__ unsigned pk2(float lo, float hi) {
  union { __hip_bfloat162 h2; unsigned u; } cv;
  cv.h2 = __float22bfloat162_rn(float2{lo, hi});
  return cv.u;
}
static __device__ __forceinline__ short f2bf_rne(float x) {
  union { float f; unsigned u; } v; v.f = x;
  unsigned r = (v.u + 0x7FFF + ((v.u >> 16) & 1)) >> 16;
  return (short)(unsigned short)r;
}
static __device__ __forceinline__ float bf2f(short h) {
  union { unsigned u; float f; } v; v.u = ((unsigned)(unsigned short)h) << 16;
  return v.f;
}
static __device__ __forceinline__ float fast_sqrt(float x) {
  float r; asm("v_sqrt_f32 %0, %1" : "=v"(r) : "v"(x)); return r;
}
static __device__ __forceinline__ float fast_exp2(float x) {
  float r; asm("v_exp_f32 %0, %1" : "=v"(r) : "v"(x)); return r;
}
static __device__ __forceinline__ void gload16(const void* g, void* l) {
  __builtin_amdgcn_global_load_lds((const __attribute__((address_space(1))) void*)g,
                                   (__attribute__((address_space(3))) void*)l, 16, 0, 0);
}

// ---------------- fused prepass ----------------
// blocks 0..1023:    K -> bf16 swizzled [bh,tile][s][e] + |k|^2
// blocks 1024..2047: V -> bf16 transposed+swizzled [bh,tile][e][s]
__global__ void prep_kv(const float* __restrict__ K, const float* __restrict__ V,
                        short* __restrict__ Kg, short* __restrict__ Vg,
                        float* __restrict__ kn2g) {
  __shared__ __align__(16) short TT[64 * 80];
  const int tid = threadIdx.x;
  const int raw = blockIdx.x;
  const bool isK = raw < 1024;
  const int bidx = isK ? raw : raw - 1024;
  const int st = bidx & 31;
  const int bh = bidx >> 5;
  const int b = bh >> 3, h = bh & 7;
  const size_t src_base = (size_t)b * (L_ * ROWSTR) + (size_t)(st * 64) * ROWSTR + (size_t)h * E_;

  if (isK) {
    short* dst = Kg + (size_t)bidx * 4096;
    const int s = tid >> 2;
    float part = 0.f;
#pragma unroll
    for (int q = 0; q < 2; ++q) {
      const int ch = (2 * tid + q) & 7;
      const int esrc = (ch ^ (s & 7)) * 8;
      const float* sp = K + src_base + (size_t)s * ROWSTR + esrc;
      const float4 a = *reinterpret_cast<const float4*>(sp);
      const float4 c4 = *reinterpret_cast<const float4*>(sp + 4);
      part += a.x*a.x + a.y*a.y + a.z*a.z + a.w*a.w
            + c4.x*c4.x + c4.y*c4.y + c4.z*c4.z + c4.w*c4.w;
      bfr8 o;
      o.u[0] = pk2(a.x, a.y);  o.u[1] = pk2(a.z, a.w);
      o.u[2] = pk2(c4.x, c4.y); o.u[3] = pk2(c4.z, c4.w);
      *reinterpret_cast<bf16x8*>(dst + s * 64 + ch * 8) = o.v;
    }
    part += __shfl_xor(part, 1);
    part += __shfl_xor(part, 2);
    if ((tid & 3) == 0) kn2g[(size_t)bidx * 64 + s] = part;
  } else {
    short* dst = Vg + (size_t)bidx * 4096;
    // phase1: rows -> bf16, row-major in LDS (paired converts, b128 writes)
    {
      const int s = tid >> 2;
      const int e0 = (tid & 3) * 16;
      const float* sp = V + src_base + (size_t)s * ROWSTR + e0;
      const float4 a0 = *reinterpret_cast<const float4*>(sp);
      const float4 a1 = *reinterpret_cast<const float4*>(sp + 4);
      const float4 a2 = *reinterpret_cast<const float4*>(sp + 8);
      const float4 a3 = *reinterpret_cast<const float4*>(sp + 12);
      bfr8 t0, t1;
      t0.u[0] = pk2(a0.x, a0.y); t0.u[1] = pk2(a0.z, a0.w);
      t0.u[2] = pk2(a1.x, a1.y); t0.u[3] = pk2(a1.z, a1.w);
      t1.u[0] = pk2(a2.x, a2.y); t1.u[1] = pk2(a2.z, a2.w);
      t1.u[2] = pk2(a3.x, a3.y); t1.u[3] = pk2(a3.z, a3.w);
      *reinterpret_cast<bf16x8*>(&TT[s * 80 + e0]) = t0.v;
      *reinterpret_cast<bf16x8*>(&TT[s * 80 + e0 + 8]) = t1.v;
    }
    __syncthreads();
    // phase2: transposed, swizzled store
    const int e = tid >> 2;
#pragma unroll
    for (int q = 0; q < 2; ++q) {
      const int ch = (2 * tid + q) & 7;
      const int s0 = (ch ^ (e & 7)) * 8;
      bfr8 o;
#pragma unroll
      for (int j = 0; j < 4; ++j) {
        const unsigned lo = (unsigned short)TT[(s0 + 2 * j) * 80 + e];
        const unsigned hi = (unsigned short)TT[(s0 + 2 * j + 1) * 80 + e];
        o.u[j] = lo | (hi << 16);
      }
      *reinterpret_cast<bf16x8*>(dst + e * 64 + ch * 8) = o.v;
    }
  }
}

// ---------------- main attention ----------------
__launch_bounds__(256, 4)
__global__ void geom_attn(const float* __restrict__ Q,
                          const short* __restrict__ Kg,
                          const short* __restrict__ Vg,
                          const float* __restrict__ kn2g,
                          float* __restrict__ out,
                          float* __restrict__ ssum_g) {
  __shared__ __align__(16) short Kl[2][4096];
  __shared__ __align__(16) short Vl[4096];
  __shared__ __align__(16) short Plds[4][16 * LDP];

  const int tid = threadIdx.x;
  const int lane = tid & 63;
  const int w = tid >> 6;
  const int g = lane >> 4;
  const int c = lane & 15;
  const int cx = c & 7;

  // XCD-chunked swizzle: each XCD owns 4 consecutive (b,h) -> 2MB K/V in its L2
  const int vbk = ((blockIdx.x & 7) << 7) + (blockIdx.x >> 3);
  const int qt = vbk & 31;
  const int bh = vbk >> 5;
  const int b = bh >> 3, h = bh & 7;
  const int q0 = qt * 64;

  const size_t qbase = (size_t)b * (L_ * ROWSTR) + (size_t)h * E_;

  // ---- Q fragments (bf16 pairs) + |q|^2 (fp32 exact)
  bfr8 qa[2];
  float qn2row[4];
  {
    const int qrow = q0 + w * 16 + c;
    const float* qp = Q + qbase + (size_t)qrow * ROWSTR;
    float qs = 0.f;
#pragma unroll
    for (int ch = 0; ch < 2; ++ch) {
      const float4 a = *reinterpret_cast<const float4*>(qp + ch * 32 + g * 8);
      const float4 b4 = *reinterpret_cast<const float4*>(qp + ch * 32 + g * 8 + 4);
      qa[ch].u[0] = pk2(a.x, a.y);  qa[ch].u[1] = pk2(a.z, a.w);
      qa[ch].u[2] = pk2(b4.x, b4.y); qa[ch].u[3] = pk2(b4.z, b4.w);
      qs += a.x*a.x + a.y*a.y + a.z*a.z + a.w*a.w
          + b4.x*b4.x + b4.y*b4.y + b4.z*b4.z + b4.w*b4.w;
    }
    qs += __shfl_xor(qs, 16);
    qs += __shfl_xor(qs, 32);
#pragma unroll
    for (int i = 0; i < 4; ++i) qn2row[i] = __shfl(qs, g * 4 + i);
  }

  float lsum[4] = {0.f, 0.f, 0.f, 0.f};
  f32x4 o[4];
#pragma unroll
  for (int dt = 0; dt < 4; ++dt) o[dt] = (f32x4){0.f, 0.f, 0.f, 0.f};
  float ssum = 0.f;

  const char* Ksrc = (const char*)(Kg + (size_t)(bh * 32) * 4096);
  const char* Vsrc = (const char*)(Vg + (size_t)(bh * 32) * 4096);
  const float* knb = kn2g + (size_t)(bh * 32) * 64;

  const int wb = w * 2048;  // wave's byte range within an 8KB tile

  float kn_cur[4], kn_next[4];
#pragma unroll
  for (int sub = 0; sub < 4; ++sub) kn_cur[sub] = knb[sub * 16 + c];

  // prologue: stage K[0]
  gload16(Ksrc + wb + lane * 16,        (char*)&Kl[0][0] + wb);
  gload16(Ksrc + wb + 1024 + lane * 16, (char*)&Kl[0][0] + wb + 1024);

  for (int kt = 0; kt < 32; ++kt) {
    const int cb = kt & 1;
    const int nx = (kt + 1) & 31;
    __syncthreads();  // vmcnt(0): K[kt] staged; Vl free (PV kt-1 done); Kl[cb^1] free

    // (1) kn prefetch for next tile -- FIRST so vmcnt(2) below drains it, not K[nx]
#pragma unroll
    for (int sub = 0; sub < 4; ++sub) kn_next[sub] = knb[nx * 64 + sub * 16 + c];
    __builtin_amdgcn_sched_barrier(0);
    // (2) V[kt] -> Vl (single buffer)
    const char* vs = Vsrc + (size_t)kt * 8192;
    gload16(vs + wb + lane * 16,        (char*)&Vl[0] + wb);
    gload16(vs + wb + 1024 + lane * 16, (char*)&Vl[0] + wb + 1024);
    // (3) K[nx] -> other K buffer (stays in flight across the counted barrier)
    const char* ks = Ksrc + (size_t)nx * 8192;
    gload16(ks + wb + lane * 16,        (char*)&Kl[cb ^ 1][0] + wb);
    gload16(ks + wb + 1024 + lane * 16, (char*)&Kl[cb ^ 1][0] + wb + 1024);

    // ---- QK^T + scores + P (log2 domain, no max subtraction)
#pragma unroll
    for (int sub = 0; sub < 4; ++sub) {
      const int s = sub * 16 + c;
      f32x4 acc = (f32x4){0.f, 0.f, 0.f, 0.f};
#pragma unroll
      for (int ch = 0; ch < 2; ++ch) {
        const int idx = s * 64 + (((ch * 4 + g) ^ cx) << 3);
        const bf16x8 bh8 = *reinterpret_cast<const bf16x8*>(&Kl[cb][idx]);
        acc = __builtin_amdgcn_mfma_f32_16x16x32_bf16(qa[ch].v, bh8, acc, 0, 0, 0);
      }
#pragma unroll
      for (int i = 0; i < 4; ++i) {
        const float dot = acc[i];
        const float w2 = fmaxf(fmaf(-dot, dot, qn2row[i] * kn_cur[sub]), EPS_);
        const float s2 = SC2_ * fast_sqrt(w2);   // score * log2(e)
        ssum += s2;
        const float p = fast_exp2(s2);           // exp(score)
        union { float f; unsigned u; } pu; pu.f = p;
        union { unsigned u; float f; } pt; pt.u = pu.u & 0xffff0000u;
        lsum[i] += pt.f;                          // sum the bf16-truncated p (exact norm)
        Plds[w][(g * 4 + i) * LDP + s] = (short)(unsigned short)(pu.u >> 16);
      }
    }

    // counted-vmcnt barrier: V[kt] (+kn) drained, K[nx] still flying
    asm volatile("s_waitcnt vmcnt(2)\n\ts_barrier" ::: "memory");

    // ---- PV: o[16x64] += P[16x64] @ V[64x64]
#pragma unroll
    for (int ks2 = 0; ks2 < 2; ++ks2) {
      const bf16x8 pa = *reinterpret_cast<const bf16x8*>(&Plds[w][c * LDP + ks2 * 32 + g * 8]);
#pragma unroll
      for (int dt = 0; dt < 4; ++dt) {
        const int er = dt * 16 + c;
        const int idx = er * 64 + (((ks2 * 4 + g) ^ cx) << 3);
        const bf16x8 vb8 = *reinterpret_cast<const bf16x8*>(&Vl[idx]);
        o[dt] = __builtin_amdgcn_mfma_f32_16x16x32_bf16(pa, vb8, o[dt], 0, 0, 0);
      }
    }
#pragma unroll
    for (int sub = 0; sub < 4; ++sub) kn_cur[sub] = kn_next[sub];
  }

  // ---- epilogue: row sums, normalize, store
#pragma unroll
  for (int m = 1; m < 16; m <<= 1)
#pragma unroll
    for (int i = 0; i < 4; ++i) lsum[i] += __shfl_xor(lsum[i], m);

#pragma unroll
  for (int i = 0; i < 4; ++i) {
    const float inv = 1.0f / lsum[i];
    const int qrow = q0 + w * 16 + g * 4 + i;
    float* op = out + (size_t)b * (L_ * ROWSTR) + (size_t)qrow * ROWSTR + (size_t)h * E_;
#pragma unroll
    for (int dt = 0; dt < 4; ++dt)
      op[dt * 16 + c] = o[dt][i] * inv;
  }

#pragma unroll
  for (int m = 1; m < 64; m <<= 1) ssum += __shfl_xor(ssum, m);
  if (lane == 0) atomicAdd(ssum_g, ssum);
}

__global__ void geom_fin(const float* __restrict__ ws, float* __restrict__ out) {
  out[(size_t)B_ * L_ * H_ * E_] = ws[0] * (LN2_ / 134217728.0f);
}

// ================= fallback (round-1 kernel) if ws too small =================
__launch_bounds__(256, 2)
__global__ void geom_attn_v1(const float* __restrict__ Q, const float* __restrict__ K,
                             const float* __restrict__ V, float* __restrict__ out,
                             float* __restrict__ score_sum) {
  __shared__ __align__(16) short Khi[64 * LDP];
  __shared__ __align__(16) short Klo[64 * LDP];
  __shared__ __align__(16) short Vt[64 * LDP];
  __shared__ __align__(16) short Plds[4][16 * LDP];
  __shared__ float kn2[64];
  __shared__ float qn2[64];

  const int tid = threadIdx.x;
  const int lane = tid & 63;
  const int w = tid >> 6;
  const int g = lane >> 4;
  const int c = lane & 15;
  const int bidx = blockIdx.x;
  const int qt = bidx & 31;
  const int h = (bidx >> 5) & 7;
  const int b = bidx >> 8;
  const int q0 = qt * 64;
  const size_t bh_base = (size_t)b * L_ * ROWSTR + (size_t)h * E_;

  bf16x8 qhi[2], qlo[2];
  {
    const int qrow = q0 + w * 16 + c;
    const float* qp = Q + bh_base + (size_t)qrow * ROWSTR;
    float qs = 0.f;
#pragma unroll
    for (int ch = 0; ch < 2; ++ch) {
      const float4 a = *reinterpret_cast<const float4*>(qp + ch * 32 + g * 8);
      const float4 bq = *reinterpret_cast<const float4*>(qp + ch * 32 + g * 8 + 4);
      const float xs[8] = {a.x,a.y,a.z,a.w,bq.x,bq.y,bq.z,bq.w};
#pragma unroll
      for (int j = 0; j < 8; ++j) {
        const float x = xs[j];
        qs += x * x;
        const short hs = f2bf_rne(x);
        qhi[ch][j] = hs;
        qlo[ch][j] = f2bf_rne(x - bf2f(hs));
      }
    }
    qs += __shfl_xor(qs, 16);
    qs += __shfl_xor(qs, 32);
    if (lane < 16) qn2[w * 16 + c] = qs;
  }
  __syncthreads();
  float qn2row[4];
#pragma unroll
  for (int i = 0; i < 4; ++i) qn2row[i] = qn2[w * 16 + g * 4 + i];

  float m_i[4] = {0,0,0,0}, lsum[4] = {0,0,0,0};
  f32x4 o[4];
#pragma unroll
  for (int dt = 0; dt < 4; ++dt) o[dt] = (f32x4){0,0,0,0};
  float ssum = 0.f;

  for (int kt = 0; kt < S_ / 64; ++kt) {
    __syncthreads();
    {
      const int r0 = tid >> 4, c4 = tid & 15;
      const size_t kbase = bh_base + (size_t)(kt * 64) * ROWSTR + c4 * 4;
      float part[4];
#pragma unroll
      for (int i = 0; i < 4; ++i) {
        const int r = r0 + 16 * i;
        const float4 kv = *reinterpret_cast<const float4*>(K + kbase + (size_t)r * ROWSTR);
        part[i] = kv.x*kv.x + kv.y*kv.y + kv.z*kv.z + kv.w*kv.w;
        const short h0 = f2bf_rne(kv.x), h1 = f2bf_rne(kv.y), h2 = f2bf_rne(kv.z), h3 = f2bf_rne(kv.w);
        bf16x4v hv = {h0, h1, h2, h3};
        *reinterpret_cast<bf16x4v*>(&Khi[r * LDP + c4 * 4]) = hv;
        bf16x4v lv = {f2bf_rne(kv.x - bf2f(h0)), f2bf_rne(kv.y - bf2f(h1)),
                      f2bf_rne(kv.z - bf2f(h2)), f2bf_rne(kv.w - bf2f(h3))};
        *reinterpret_cast<bf16x4v*>(&Klo[r * LDP + c4 * 4]) = lv;
        const float4 vv = *reinterpret_cast<const float4*>(V + kbase + (size_t)r * ROWSTR);
        Vt[(c4 * 4 + 0) * LDP + r] = f2bf_rne(vv.x);
        Vt[(c4 * 4 + 1) * LDP + r] = f2bf_rne(vv.y);
        Vt[(c4 * 4 + 2) * LDP + r] = f2bf_rne(vv.z);
        Vt[(c4 * 4 + 3) * LDP + r] = f2bf_rne(vv.w);
      }
#pragma unroll
      for (int m = 1; m < 16; m <<= 1)
#pragma unroll
        for (int i = 0; i < 4; ++i) part[i] += __shfl_xor(part[i], m);
      if (c4 < 4) kn2[r0 + 16 * c4] = part[c4];
    }
    __syncthreads();

    float sv[4][4];
    float tm[4] = {0,0,0,0};
#pragma unroll
    for (int sub = 0; sub < 4; ++sub) {
      const int s = sub * 16 + c;
      f32x4 acc = (f32x4){0,0,0,0};
#pragma unroll
      for (int ch = 0; ch < 2; ++ch) {
        const int e = ch * 32 + g * 8;
        const bf16x8 bh8 = *reinterpret_cast<const bf16x8*>(&Khi[s * LDP + e]);
        const bf16x8 bl8 = *reinterpret_cast<const bf16x8*>(&Klo[s * LDP + e]);
        acc = __builtin_amdgcn_mfma_f32_16x16x32_bf16(qhi[ch], bh8, acc, 0, 0, 0);
        acc = __builtin_amdgcn_mfma_f32_16x16x32_bf16(qlo[ch], bh8, acc, 0, 0, 0);
        acc = __builtin_amdgcn_mfma_f32_16x16x32_bf16(qhi[ch], bl8, acc, 0, 0, 0);
      }
      const float kn = kn2[s];
#pragma unroll
      for (int i = 0; i < 4; ++i) {
        const float dot = acc[i];
        float w2 = fmaxf(qn2row[i] * kn - dot * dot, 0.f) + EPS_;
        const float sc = 0.125f * sqrtf(w2);
        sv[sub][i] = sc;
        tm[i] = fmaxf(tm[i], sc);
        ssum += sc;
      }
    }
#pragma unroll
    for (int m = 1; m < 16; m <<= 1)
#pragma unroll
      for (int i = 0; i < 4; ++i) tm[i] = fmaxf(tm[i], __shfl_xor(tm[i], m));
    float r_[4];
#pragma unroll
    for (int i = 0; i < 4; ++i) {
      const float mn = fmaxf(m_i[i], tm[i]);
      r_[i] = __expf(m_i[i] - mn);
      m_i[i] = mn;
      lsum[i] *= r_[i];
    }
#pragma unroll
    for (int dt = 0; dt < 4; ++dt)
#pragma unroll
      for (int i = 0; i < 4; ++i) o[dt][i] *= r_[i];
#pragma unroll
    for (int sub = 0; sub < 4; ++sub) {
      const int s = sub * 16 + c;
#pragma unroll
      for (int i = 0; i < 4; ++i) {
        const float p = __expf(sv[sub][i] - m_i[i]);
        lsum[i] += p;
        Plds[w][(g * 4 + i) * LDP + s] = f2bf_rne(p);
      }
    }
    __syncthreads();
#pragma unroll
    for (int ks = 0; ks < 2; ++ks) {
      const bf16x8 pa = *reinterpret_cast<const bf16x8*>(&Plds[w][c * LDP + ks * 32 + g * 8]);
#pragma unroll
      for (int dt = 0; dt < 4; ++dt) {
        const bf16x8 vb8 = *reinterpret_cast<const bf16x8*>(&Vt[(dt * 16 + c) * LDP + ks * 32 + g * 8]);
        o[dt] = __builtin_amdgcn_mfma_f32_16x16x32_bf16(pa, vb8, o[dt], 0, 0, 0);
      }
    }
  }
#pragma unroll
  for (int m = 1; m < 16; m <<= 1)
#pragma unroll
    for (int i = 0; i < 4; ++i) lsum[i] += __shfl_xor(lsum[i], m);
#pragma unroll
  for (int i = 0; i < 4; ++i) {
    const float inv = 1.0f / lsum[i];
    const int qrow = q0 + w * 16 + g * 4 + i;
    float* op = out + (size_t)b * L_ * ROWSTR + (size_t)qrow * ROWSTR + (size_t)h * E_;
#pragma unroll
    for (int dt = 0; dt < 4; ++dt) op[dt * 16 + c] = o[dt][i] * inv;
  }
#pragma unroll
  for (int m = 1; m < 64; m <<= 1) ssum += __shfl_xor(ssum, m);
  if (lane == 0) atomicAdd(score_sum, ssum);
}

__global__ void geom_fin_v1(const float* __restrict__ ws, float* __restrict__ out) {
  out[(size_t)B_ * L_ * H_ * E_] = ws[0] * (1.0f / 134217728.0f);
}

extern "C" void kernel_launch(void* const* d_in, const int* in_sizes, int n_in,
                              void* d_out, int out_size, void* d_ws, size_t ws_size,
                              hipStream_t stream) {
  const float* Q = (const float*)d_in[0];
  const float* K = (const float*)d_in[1];
  const float* V = (const float*)d_in[2];
  float* out = (float*)d_out;

  if (ws_size >= (size_t)WS_NEED) {
    short* Kg = (short*)((char*)d_ws + K_OFF);
    short* Vg = (short*)((char*)d_ws + V_OFF);
    float* kn2g = (float*)((char*)d_ws + KN_OFF);
    float* ss = (float*)((char*)d_ws + SS_OFF);
    hipMemsetAsync(ss, 0, sizeof(float), stream);
    prep_kv<<<dim3(2048), dim3(256), 0, stream>>>(K, V, Kg, Vg, kn2g);
    geom_attn<<<dim3(1024), dim3(256), 0, stream>>>(Q, Kg, Vg, kn2g, out, ss);
    geom_fin<<<dim3(1), dim3(1), 0, stream>>>(ss, out);
  } else {
    float* ss = (float*)d_ws;
    hipMemsetAsync(ss, 0, sizeof(float), stream);
    geom_attn_v1<<<dim3(1024), dim3(256), 0, stream>>>(Q, K, V, out, ss);
    geom_fin_v1<<<dim3(1), dim3(1), 0, stream>>>(ss, out);
  }
}